// Round 12
// baseline (126365.747 us; speedup 1.0000x reference)
//
#include <hip/hip_runtime.h>
#include <cstdint>
#include <cstddef>
#include <math.h>

// Exact Viterbi decode: N=512 states, T=8192, M=50257 tokens.
// R12: single-wave forward + glds-STAGED scan.
// R11 decode: single-wave everything-but-scan = 2.3k cy/step (vs 8.9k for
// the 8-wave skeleton), but the scan = n x ~800cy serialized loads (compiler
// re-serializes register load pipelines; 3rd confirmation). Fix: stage
// survivor rows via __builtin_amdgcn_global_load_lds (fire-and-forget, no
// dest VGPRs => nothing to serialize), ONE vmcnt(0) per batch, scan from LDS.
// Exactness (same proof chain, R11-verified logic for selection/extras):
//   SV = {i : v_i >= globalmax - DELTA_W} (argmax in => n>=1), ASCENDING idx;
//   T  = min_c (achieved col max over SV);
//   fl(v_i + rowmax_i) < T => row i can't win/tie (IEEE add monotone);
//   extras {fl(v+rowmax)>=T} \ SV merged inline exactly (full tie-break).
//   Ascending SV + strict > merge == first-index argmax. Adds single-rounded.

#define NT 512
#define TT 8192
#define MT 50257
#define DELTA_W 0.15f
#define NEG_INF (-3.402823466e38f)

typedef float  f32x4 __attribute__((ext_vector_type(4)));
typedef unsigned u32x4 __attribute__((ext_vector_type(4)));

#define BT_L 32                  // backtrace segment length
#define BT_S (TT / BT_L)         // 256 segments
#define SB 64                    // staged rows per batch (128 KiB)

// ---- workspace layout (bytes) ----
#define WS_LOGPI   0u            // 512 f32
#define WS_VLAST   2048u         // 512 f32
#define WS_BOUND   4096u         // 257 i32
#define WS_ROWMAX  5632u         // 512 f32
#define WS_MAPS    8192u         // 256*512 u16 = 262144
#define WS_LA      270336u       // 512*512 f32 = 1048576 (row-major logA)
#define WS_EMIS    1318912u      // 8192*512 f32 = 16777216 (diag scratch after fwd)
#define WS_BP      18096128u     // 8192*512 u16 = 8388608
#define WS_NEED    26484736u

// Correctly-rounded fp32 logs via fp64 (verified: absmax 0 vs numpy ref).
__global__ void prep_logs(const float* __restrict__ A, const float* __restrict__ Pi,
                          float* __restrict__ lA, float* __restrict__ logPi) {
    int idx = blockIdx.x * blockDim.x + threadIdx.x;
    if (idx < NT * NT) {
        lA[idx] = (float)log((double)A[idx]);
    } else if (idx < NT * NT + NT) {
        int j = idx - NT * NT;
        logPi[j] = (float)log((double)Pi[j]);
    }
}

__global__ void prep_rowmax(const float* __restrict__ lA, float* __restrict__ rowmax) {
    __shared__ float s[4];
    int i = blockIdx.x;
    int t = threadIdx.x;                    // 256 threads
    float m = fmaxf(lA[i * NT + t], lA[i * NT + t + 256]);
    for (int k = 32; k >= 1; k >>= 1) m = fmaxf(m, __shfl_xor(m, k, 64));
    if ((t & 63) == 0) s[t >> 6] = m;
    __syncthreads();
    if (t == 0) {
        float r = fmaxf(fmaxf(s[0], s[1]), fmaxf(s[2], s[3]));
        rowmax[i] = r;
    }
}

__global__ void prep_emis(const float* __restrict__ B, const int* __restrict__ tok,
                          float* __restrict__ emis) {
    int idx = blockIdx.x * blockDim.x + threadIdx.x;   // t*512 + j
    if (idx >= TT * NT) return;
    int t = idx >> 9;
    int j = idx & (NT - 1);
    int tk = tok[t];
    float e;
    if (tk < 0) e = (float)log((double)(1.0f / 512.0f));
    else        e = (float)log((double)B[(size_t)j * MT + tk]);
    emis[idx] = e;
}

// async global->LDS, 16 B per lane (per-lane gptr; wave-uniform lptr + lane*16 dest)
__device__ __forceinline__ void glds16(const float* g, float* l) {
    __builtin_amdgcn_global_load_lds(
        (const __attribute__((address_space(1))) void*)g,
        (__attribute__((address_space(3))) void*)l, 16, 0, 0);
}

// ONE wave, 64 threads. Lane l owns columns/rows l*8+k. No barriers.
__launch_bounds__(64, 1)
__global__ void viterbi_fwd_exact(const float* __restrict__ lA,
                                  const float* __restrict__ rowmax,
                                  const float* emis,          // aliases diag scratch
                                  const float* __restrict__ logPi,
                                  unsigned short* __restrict__ bp,
                                  float* __restrict__ vlast,
                                  float* scratch) {
    __shared__ float2 SV[520];               // survivors (v, idx bits), ascending idx
    __shared__ float2 SVX[520];              // extras (rare), ascending idx
    __shared__ alignas(16) float stage[SB * NT];   // 128 KiB staged lA rows

    const int lane = threadIdx.x;            // 0..63
    const int j0   = lane << 3;              // first owned column/row
    const unsigned long long below = (1ull << lane) - 1ull;

    // ---- preamble: warm lA into L2; rmax; v0; emis prefetch ----
    float acc = 0.0f;
    {
        const float4* lAf4 = (const float4*)lA;
        for (int k = lane; k < (NT * NT) / 4; k += 64) acc += lAf4[k].x;
    }
    float rmax[8];
    {
        const float4* rp = (const float4*)(rowmax + j0);
        float4 r0 = rp[0], r1 = rp[1];
        rmax[0]=r0.x; rmax[1]=r0.y; rmax[2]=r0.z; rmax[3]=r0.w;
        rmax[4]=r1.x; rmax[5]=r1.y; rmax[6]=r1.z; rmax[7]=r1.w;
    }
    float v[8];
    {
        const float4* lp = (const float4*)(logPi + j0);
        const float4* ep = (const float4*)(emis + j0);
        float4 l0 = lp[0], l1 = lp[1], e0 = ep[0], e1 = ep[1];
        v[0]=l0.x+e0.x; v[1]=l0.y+e0.y; v[2]=l0.z+e0.z; v[3]=l0.w+e0.w;
        v[4]=l1.x+e1.x; v[5]=l1.y+e1.y; v[6]=l1.z+e1.z; v[7]=l1.w+e1.w;
    }
    if (acc == 1.2345e30f && lane == 63) SVX[0].x = acc;   // keep warm loads alive

    float en[8];                             // emis[t] prefetch
    {
        const f32x4* ep = (const f32x4*)(emis + (size_t)NT + j0);
        f32x4 e0 = __builtin_nontemporal_load(ep);
        f32x4 e1 = __builtin_nontemporal_load(ep + 1);
        en[0]=e0.x; en[1]=e0.y; en[2]=e0.z; en[3]=e0.w;
        en[4]=e1.x; en[5]=e1.y; en[6]=e1.z; en[7]=e1.w;
    }
    long long c0 = clock64();
    long long nAcc = 0;

    for (int t = 1; t < TT; ++t) {
        // ---- emis carry + prefetch(t+1) ----
        float e[8];
        #pragma unroll
        for (int k = 0; k < 8; ++k) e[k] = en[k];
        {
            const int tn = (t + 1 < TT) ? t + 1 : TT - 1;
            const f32x4* ep = (const f32x4*)(emis + (size_t)tn * NT + j0);
            f32x4 e0 = __builtin_nontemporal_load(ep);
            f32x4 e1 = __builtin_nontemporal_load(ep + 1);
            en[0]=e0.x; en[1]=e0.y; en[2]=e0.z; en[3]=e0.w;
            en[4]=e1.x; en[5]=e1.y; en[6]=e1.z; en[7]=e1.w;
        }

        // ---- selection: global max window; compact ascending (lex lane,k) ----
        float lm = v[0];
        #pragma unroll
        for (int k = 1; k < 8; ++k) lm = fmaxf(lm, v[k]);
        float wm = lm;
        #pragma unroll
        for (int d = 1; d <= 32; d <<= 1) wm = fmaxf(wm, __shfl_xor(wm, d, 64));
        const float thr = wm - DELTA_W;      // argmax always selected => n>=1
        bool pr[8];
        unsigned long long mk[8];
        #pragma unroll
        for (int k = 0; k < 8; ++k) { pr[k] = (v[k] >= thr); mk[k] = __ballot(pr[k]); }
        int myBase = 0, n = 0;
        #pragma unroll
        for (int k = 0; k < 8; ++k) {
            myBase += (int)__popcll(mk[k] & below);
            n      += (int)__popcll(mk[k]);
        }
        {
            int pos = myBase;
            #pragma unroll
            for (int k = 0; k < 8; ++k)
                if (pr[k]) { SV[pos] = make_float2(v[k], __int_as_float(j0 + k)); ++pos; }
        }
        nAcc += n;

        // ---- scan: glds-staged batches; LDS read + strict-> merge ----
        float mv[8]; int bi[8];
        #pragma unroll
        for (int k = 0; k < 8; ++k) { mv[k] = NEG_INF; bi[k] = 0x7fffffff; }
        for (int s0 = 0; s0 < n; s0 += SB) {
            const int bcnt = (n - s0 < SB) ? (n - s0) : SB;
            asm volatile("" ::: "memory");   // no DMA hoist above prior reads
            #pragma unroll 4
            for (int s = 0; s < bcnt; ++s) { // issue: fire-and-forget DMA
                const int idx = __float_as_int(SV[s0 + s].y);
                const float* gp = lA + ((size_t)(unsigned)idx << 9) + (lane << 2);
                glds16(gp,       &stage[s * NT]);
                glds16(gp + 256, &stage[s * NT + 256]);
            }
            asm volatile("s_waitcnt vmcnt(0)" ::: "memory");   // loads landed
            #pragma unroll 4
            for (int s = 0; s < bcnt; ++s) { // ascending order => strict >
                const float2 sv = SV[s0 + s];
                const int ii = __float_as_int(sv.y);
                const f32x4* sp = (const f32x4*)&stage[s * NT + j0];
                f32x4 ca = sp[0], cb = sp[1];
                float c[8] = {ca.x,ca.y,ca.z,ca.w, cb.x,cb.y,cb.z,cb.w};
                #pragma unroll
                for (int k = 0; k < 8; ++k) {
                    float sc = sv.x + c[k];  // single-rounded add == ref
                    if (sc > mv[k]) { mv[k] = sc; bi[k] = ii; }
                }
            }
        }

        // ---- T (achieved col max over SV, pre-extras); extras inline ----
        float tl = mv[0];
        #pragma unroll
        for (int k = 1; k < 8; ++k) tl = fminf(tl, mv[k]);
        float T = tl;
        #pragma unroll
        for (int d = 1; d <= 32; d <<= 1) T = fminf(T, __shfl_xor(T, d, 64));
        bool px[8];
        unsigned long long mx[8];
        #pragma unroll
        for (int k = 0; k < 8; ++k) {
            px[k] = (v[k] + rmax[k] >= T) && !pr[k];   // fl monotone bound
            mx[k] = __ballot(px[k]);
        }
        int nX = 0;
        #pragma unroll
        for (int k = 0; k < 8; ++k) nX += (int)__popcll(mx[k]);
        if (nX > 0) {                        // small tail (fires often, tiny)
            int xb = 0;
            #pragma unroll
            for (int k = 0; k < 8; ++k) xb += (int)__popcll(mx[k] & below);
            {
                int pos = xb;
                #pragma unroll
                for (int k = 0; k < 8; ++k)
                    if (px[k]) { SVX[pos] = make_float2(v[k], __int_as_float(j0 + k)); ++pos; }
            }
            const float* lAbase = lA + j0;
            const int nXm1 = nX - 1;
            for (int sx = 0; sx < nX; sx += 4) {
                float vE[4]; int iE[4]; float4 e0[4], e1[4];
                #pragma unroll
                for (int q = 0; q < 4; ++q) {
                    int ss = sx + q; int gs = ss < nXm1 ? ss : nXm1;
                    float2 sv = SVX[gs];
                    vE[q] = sv.x; iE[q] = __float_as_int(sv.y);
                    const float4* rp = (const float4*)(lAbase + ((size_t)(unsigned)iE[q] << 9));
                    e0[q] = rp[0]; e1[q] = rp[1];
                }
                #pragma unroll
                for (int q = 0; q < 4; ++q) {     // full tie-break (out of order vs SV)
                    float c[8] = {e0[q].x,e0[q].y,e0[q].z,e0[q].w,
                                  e1[q].x,e1[q].y,e1[q].z,e1[q].w};
                    #pragma unroll
                    for (int k = 0; k < 8; ++k) {
                        float sc = vE[q] + c[k];
                        if (sc > mv[k] || (sc == mv[k] && iE[q] < bi[k])) {
                            mv[k] = sc; bi[k] = iE[q];
                        }
                    }
                }
            }
        }

        // ---- finalize: vn, packed bp store ----
        #pragma unroll
        for (int k = 0; k < 8; ++k) v[k] = mv[k] + e[k];   // single-rounded == ref
        {
            u32x4 pk;
            pk.x = ((unsigned)bi[0] & 0xFFFFu) | ((unsigned)bi[1] << 16);
            pk.y = ((unsigned)bi[2] & 0xFFFFu) | ((unsigned)bi[3] << 16);
            pk.z = ((unsigned)bi[4] & 0xFFFFu) | ((unsigned)bi[5] << 16);
            pk.w = ((unsigned)bi[6] & 0xFFFFu) | ((unsigned)bi[7] << 16);
            __builtin_nontemporal_store(pk, (u32x4*)(bp + (size_t)t * NT + j0));
        }
        if (t == TT - 1) {
            float4* vp = (float4*)(vlast + j0);
            vp[0] = make_float4(v[0], v[1], v[2], v[3]);
            vp[1] = make_float4(v[4], v[5], v[6], v[7]);
        }
    }

    // ---- diagnostics: P = min(255,cyc>>8)*16 + min(15, mean_n>>4) ----
    // decode: P = 2*(WRITE_KB - 8193); cb = P>>4 (256-cy buckets); nb = P&15.
    {
        long long cyc = (clock64() - c0) / (long long)(TT - 1);
        int cb = (int)(cyc >> 8); if (cb > 255) cb = 255; if (cb < 0) cb = 0;
        int mn = (int)(nAcc / (long long)(TT - 1));
        int nb = mn >> 4; if (nb > 15) nb = 15;
        const int P = cb * 16 + nb;
        for (int pg = 0; pg < P; ++pg) {
            unsigned long long val = ((unsigned long long)pg << 32) | (unsigned)lane;
            __builtin_nontemporal_store(val,
                (unsigned long long*)((char*)scratch + (size_t)pg * 4096) + lane);
        }
    }
}

// ---- backtrace: per-segment map composition (verified exact) ----
__launch_bounds__(NT, 1)
__global__ void bt_maps(const unsigned short* __restrict__ bp,
                        unsigned short* __restrict__ maps) {
    __shared__ unsigned short bps[BT_L * NT];
    const int s = blockIdx.x;
    const int tlo = BT_L * s + 1;
    int thi = BT_L * (s + 1); if (thi > TT - 1) thi = TT - 1;
    const int nt = thi - tlo + 1;
    for (int k = threadIdx.x; k < nt * NT; k += NT)
        bps[k] = bp[(size_t)tlo * NT + k];
    __syncthreads();
    int cur = threadIdx.x;
    for (int r = nt - 1; r >= 0; --r) cur = bps[r * NT + cur];
    maps[s * NT + threadIdx.x] = (unsigned short)cur;
}

__launch_bounds__(NT, 1)
__global__ void bt_bound(const float* __restrict__ vlast,
                         const unsigned short* __restrict__ maps,
                         int* __restrict__ bound) {
    __shared__ float sv[NT];
    __shared__ int   si[NT];
    int j = threadIdx.x;
    sv[j] = vlast[j]; si[j] = j;
    __syncthreads();
    for (int off = NT / 2; off > 0; off >>= 1) {
        if (j < off) {
            float v2 = sv[j + off]; int i2 = si[j + off];
            if (v2 > sv[j] || (v2 == sv[j] && i2 < si[j])) { sv[j] = v2; si[j] = i2; }
        }
        __syncthreads();
    }
    if (j == 0) {
        int cur = si[0];
        bound[BT_S] = cur;
        for (int s = BT_S - 1; s >= 0; --s) {
            cur = maps[s * NT + cur];
            bound[s] = cur;
        }
    }
}

__launch_bounds__(NT, 1)
__global__ void bt_path(const unsigned short* __restrict__ bp,
                        const int* __restrict__ bound,
                        int* __restrict__ path) {
    __shared__ unsigned short bps[BT_L * NT];
    const int s = blockIdx.x;
    const int tlo = BT_L * s + 1;
    int thi = BT_L * (s + 1); if (thi > TT - 1) thi = TT - 1;
    const int nt = thi - tlo + 1;
    for (int k = threadIdx.x; k < nt * NT; k += NT)
        bps[k] = bp[(size_t)tlo * NT + k];
    __syncthreads();
    if (threadIdx.x == 0) {
        int cur = bound[s + 1];
        if (s == BT_S - 1) path[TT - 1] = cur;
        for (int r = nt - 1; r >= 0; --r) {
            cur = bps[r * NT + cur];
            path[tlo - 1 + r] = cur;
        }
    }
}

extern "C" void kernel_launch(void* const* d_in, const int* in_sizes, int n_in,
                              void* d_out, int out_size, void* d_ws, size_t ws_size,
                              hipStream_t stream) {
    const int*   tok = (const int*)d_in[0];
    const float* A   = (const float*)d_in[1];
    const float* B   = (const float*)d_in[2];
    const float* Pi  = (const float*)d_in[3];
    int* path = (int*)d_out;
    char* ws = (char*)d_ws;
    if (ws_size < (size_t)WS_NEED) return;

    float* logPi          = (float*)(ws + WS_LOGPI);
    float* vlast          = (float*)(ws + WS_VLAST);
    int*   bound          = (int*)(ws + WS_BOUND);
    float* rowmax         = (float*)(ws + WS_ROWMAX);
    unsigned short* maps  = (unsigned short*)(ws + WS_MAPS);
    float* lA             = (float*)(ws + WS_LA);
    float* emis           = (float*)(ws + WS_EMIS);
    unsigned short* bpp   = (unsigned short*)(ws + WS_BP);

    prep_logs  <<<(NT * NT + NT + 255) / 256, 256, 0, stream>>>(A, Pi, lA, logPi);
    prep_emis  <<<(TT * NT) / 256,            256, 0, stream>>>(B, tok, emis);
    prep_rowmax<<<NT, 256, 0, stream>>>(lA, rowmax);
    viterbi_fwd_exact<<<1, 64, 0, stream>>>(lA, rowmax, emis, logPi, bpp, vlast,
                                            emis /*diag scratch*/);
    bt_maps  <<<BT_S, NT, 0, stream>>>(bpp, maps);
    bt_bound <<<1,    NT, 0, stream>>>(vlast, maps, bound);
    bt_path  <<<BT_S, NT, 0, stream>>>(bpp, bound, path);
}

// Round 13
// 56223.938 us; speedup vs baseline: 2.2475x; 2.2475x over previous
//
#include <hip/hip_runtime.h>
#include <cstdint>
#include <cstddef>
#include <math.h>

// Exact Viterbi decode: N=512 states, T=8192, M=50257 tokens.
// R13 = R9 (8-wave row-parallel, 4 barriers, inline extras — verified 55ms)
// + per-wave glds-STAGED scan:
//   wave w stages its survivor rows (w, w+8, ...) into its PRIVATE LDS
//   region via global_load_lds (fire-and-forget, no dest VGPRs => compiler
//   cannot re-serialize: the failure mode measured in R8/R9/R11/R12 at
//   VGPR=60/76/92/132), ONE s_waitcnt vmcnt(0) per batch, NO new barriers
//   (own-region reads need no cross-wave sync). Stage reads use the
//   col = lane+64k mapping => conflict-free (R12's 2.8M conflicts were a
//   lane*8-stride read mistake). lgkmcnt(0) before issue guards the
//   ds_read / DMA-write race on slot reuse.
// Evidence: single-wave (R11/R12) = 34-37k cy/step vs 8-wave R9 = 15.9k
// (scan 7k + skeleton 8.9k) => TLP is the only working latency hiding;
// this round removes the scan's serialized ~900cy/row-group fetches.
// Exactness (same proof chain as R0-R9, R9 logic verbatim elsewhere):
//   SV = union over waves {i : v_i >= wavemax - DELTA_W} (each wave's max
//   in => n>=8, every wave has >=1 row); T = min_c achieved col max over SV;
//   fl(v_i + rowmax_i) < T => row i can't win/tie (IEEE add monotone);
//   extras {fl(v+rowmax)>=T} \ SV merged inline exactly. All merges strict >
//   with tie -> smaller row index => exact first-index argmax.

#define NT 512
#define TT 8192
#define MT 50257
#define DELTA_W 0.15f
#define NEG_INF (-3.402823466e38f)

#define BT_L 32                  // backtrace segment length
#define BT_S (TT / BT_L)         // 256 segments
#define SBW 6                    // staged rows per wave per batch (12 KiB/wave)

// ---- workspace layout (bytes) ----
#define WS_LOGPI   0u            // 512 f32
#define WS_VLAST   2048u         // 512 f32
#define WS_BOUND   4096u         // 257 i32
#define WS_ROWMAX  5632u         // 512 f32
#define WS_MAPS    8192u         // 256*512 u16 = 262144
#define WS_LA      270336u       // 512*512 f32 = 1048576 (row-major logA)
#define WS_EMIS    1318912u      // 8192*512 f32 = 16777216 (diag scratch after fwd)
#define WS_BP      18096128u     // 8192*512 u16 = 8388608
#define WS_NEED    26484736u

// Correctly-rounded fp32 logs via fp64 (verified: absmax 0 vs numpy ref).
__global__ void prep_logs(const float* __restrict__ A, const float* __restrict__ Pi,
                          float* __restrict__ lA, float* __restrict__ logPi) {
    int idx = blockIdx.x * blockDim.x + threadIdx.x;
    if (idx < NT * NT) {
        lA[idx] = (float)log((double)A[idx]);
    } else if (idx < NT * NT + NT) {
        int j = idx - NT * NT;
        logPi[j] = (float)log((double)Pi[j]);
    }
}

__global__ void prep_rowmax(const float* __restrict__ lA, float* __restrict__ rowmax) {
    __shared__ float s[4];
    int i = blockIdx.x;
    int t = threadIdx.x;                    // 256 threads
    float m = fmaxf(lA[i * NT + t], lA[i * NT + t + 256]);
    for (int k = 32; k >= 1; k >>= 1) m = fmaxf(m, __shfl_xor(m, k, 64));
    if ((t & 63) == 0) s[t >> 6] = m;
    __syncthreads();
    if (t == 0) {
        float r = fmaxf(fmaxf(s[0], s[1]), fmaxf(s[2], s[3]));
        rowmax[i] = r;
    }
}

__global__ void prep_emis(const float* __restrict__ B, const int* __restrict__ tok,
                          float* __restrict__ emis) {
    int idx = blockIdx.x * blockDim.x + threadIdx.x;   // t*512 + j
    if (idx >= TT * NT) return;
    int t = idx >> 9;
    int j = idx & (NT - 1);
    int tk = tok[t];
    float e;
    if (tk < 0) e = (float)log((double)(1.0f / 512.0f));
    else        e = (float)log((double)B[(size_t)j * MT + tk]);
    emis[idx] = e;
}

// async global->LDS, 16 B per lane (per-lane gptr; wave-uniform lptr + lane*16 dest)
__device__ __forceinline__ void glds16(const float* g, float* l) {
    __builtin_amdgcn_global_load_lds(
        (const __attribute__((address_space(1))) void*)g,
        (__attribute__((address_space(3))) void*)l, 16, 0, 0);
}

// 512 threads / 8 waves. 4 barriers per step (common path).
__launch_bounds__(NT, 1)
__global__ void viterbi_fwd_exact(const float* __restrict__ lA,
                                  const float* __restrict__ rowmax,
                                  const float* emis,          // aliases diag scratch
                                  const float* __restrict__ logPi,
                                  unsigned short* __restrict__ bp,
                                  float* __restrict__ vlast,
                                  float* scratch) {
    __shared__ float2 SV[2][560];            // double-buffered survivors (v, idx bits)
    __shared__ float2 SVX[560];              // extras (rare)
    __shared__ alignas(16) float redR[8];    // rowmax partials
    __shared__ alignas(16) float redT[8];    // T partials
    __shared__ int nCtr[2];
    __shared__ int nCtrX;
    __shared__ int Pshare;
    __shared__ float2 part[8][NT];           // per-wave column partials (32 KiB)
    __shared__ alignas(16) float stageW[8][SBW][NT];   // 96 KiB per-wave staged rows

    const int tid  = threadIdx.x;
    const int j    = tid;                    // column AND row owned
    const int lane = tid & 63;
    const int wave = tid >> 6;               // 0..7
    const unsigned long long below = (1ull << lane) - 1ull;
    const float* __restrict__ lAj = lA + j;

    // ---- preamble: warm lA into L2; R per-row copy; counters; v0 ----
    float acc = 0.0f;
    {
        const float4* lAf4 = (const float4*)lA;
        for (int k = tid; k < (NT * NT) / 4; k += NT) acc += lAf4[k].x;
    }
    float r = rowmax[j];
    const float rmaxOwn = r;                 // per-row bound (tighter than global R)
    #pragma unroll
    for (int d = 1; d <= 32; d <<= 1) r = fmaxf(r, __shfl_xor(r, d, 64));
    if (lane == 0) redR[wave] = r;
    if (tid == 0) { nCtr[0] = 0; nCtr[1] = 0; nCtrX = 0; }
    __syncthreads();
    if (acc == 1.2345e30f && j == 511) SVX[0].x = acc;   // keep warm loads alive

    float v = logPi[j] + emis[j];            // exact v0 (single-rounded == ref)
    float e_next = __builtin_nontemporal_load(emis + (size_t)NT + j);   // emis[1]
    long long c0 = 0, nAcc = 0;
    if (tid == 0) c0 = clock64();

    for (int t = 1; t < TT; ++t) {
        const int p = t & 1;
        // ---- PH1: emis carry + prefetch(t+1); per-wave select; compact ----
        const float e = e_next;
        {
            const int tn = (t + 1 < TT) ? t + 1 : TT - 1;
            e_next = __builtin_nontemporal_load(emis + (size_t)tn * NT + j);
        }
        float wm = v;
        #pragma unroll
        for (int d = 1; d <= 32; d <<= 1) wm = fmaxf(wm, __shfl_xor(wm, d, 64));
        bool pred = (v >= wm - DELTA_W);     // per-wave max always selected
        unsigned long long mk = __ballot(pred);
        int base = 0;
        if (lane == 0) base = atomicAdd(&nCtr[p], __popcll(mk));
        base = __shfl(base, 0, 64);
        if (pred) SV[p][base + __popcll(mk & below)] = make_float2(v, __int_as_float(j));
        __syncthreads();                     // B1: survivors final

        const int n = nCtr[p];               // >= 8 (block-uniform)
        if (tid == 0) { nCtr[p ^ 1] = 0; nCtrX = 0; }   // consumed pre-B1 / pre-B3
        nAcc += n;

        // ---- PH2a: per-wave glds-staged scan (no cross-wave sync) ----
        float mv[8]; int bi[8];
        #pragma unroll
        for (int k = 0; k < 8; ++k) { mv[k] = NEG_INF; bi[k] = 0x7fffffff; }
        {
            const int nw = (n - wave + 7) >> 3;          // rows this wave (>=1: n>=8)
            float* stw = &stageW[wave][0][0];
            for (int b0 = 0; b0 < nw; b0 += SBW) {
                const int bc = (nw - b0 < SBW) ? (nw - b0) : SBW;
                asm volatile("s_waitcnt lgkmcnt(0)" ::: "memory");  // prior LDS reads done
                for (int q = 0; q < bc; ++q) {           // fire-and-forget DMA
                    const int s = wave + ((b0 + q) << 3);
                    const int idx = __float_as_int(SV[p][s].y);
                    const float* gp = lA + ((size_t)(unsigned)idx << 9) + (lane << 2);
                    glds16(gp,       stw + q * NT);
                    glds16(gp + 256, stw + q * NT + 256);
                }
                asm volatile("s_waitcnt vmcnt(0)" ::: "memory");    // DMA landed
                for (int q = 0; q < bc; ++q) {
                    const int s = wave + ((b0 + q) << 3);
                    const float2 sv = SV[p][s];
                    const int ii = __float_as_int(sv.y);
                    const float* rp = stw + q * NT + lane;   // col lane+64k: conflict-free
                    #pragma unroll
                    for (int k = 0; k < 8; ++k) {
                        float sc = sv.x + rp[k << 6];        // single-rounded add == ref
                        if (sc > mv[k] || (sc == mv[k] && ii < bi[k])) {
                            mv[k] = sc; bi[k] = ii;
                        }
                    }
                }
            }
        }
        // write partials: col lane+64k -> part[wave][lane+(k<<6)] (R9: 0 conflicts)
        #pragma unroll
        for (int k = 0; k < 8; ++k)
            part[wave][lane + (k << 6)] = make_float2(mv[k], __int_as_float(bi[k]));
        __syncthreads();                     // B2: partials visible

        // ---- PH2b: merge 8 partials for column j; tmin; redT ----
        float mval = NEG_INF;
        int   bidx = 0x7fffffff;
        #pragma unroll
        for (int w = 0; w < 8; ++w) {
            const float2 q = part[w][j];
            const float val = q.x;
            const int   ii  = __float_as_int(q.y);
            if (val > mval || (val == mval && ii < bidx)) { mval = val; bidx = ii; }
        }
        float tmin = mval;
        #pragma unroll
        for (int d = 1; d <= 32; d <<= 1) tmin = fminf(tmin, __shfl_xor(tmin, d, 64));
        if (lane == 0) redT[wave] = tmin;
        __syncthreads();                     // B3: redT visible

        // ---- PH2c: T; extras compact (rare; per-row bound) ----
        float4 t0 = *(const float4*)redT;
        float4 t1 = *(const float4*)(redT + 4);
        float T = fminf(fminf(fminf(t0.x, t0.y), fminf(t0.z, t0.w)),
                        fminf(fminf(t1.x, t1.y), fminf(t1.z, t1.w)));
        bool px = (v + rmaxOwn >= T) && !pred;   // fl(v+rmax_j) monotone bound
        unsigned long long mkx = __ballot(px);
        if (mkx != 0ull) {                   // rare
            int bx = 0;
            if (lane == 0) bx = atomicAdd(&nCtrX, __popcll(mkx));
            bx = __shfl(bx, 0, 64);
            if (px) SVX[bx + __popcll(mkx & below)] = make_float2(v, __int_as_float(j));
        }
        __syncthreads();                     // B4: SVX/nCtrX visible

        // ---- PH2d: rare extras scan (serial gather); finalize ----
        const int nX = nCtrX;                // block-uniform
        if (nX > 0) {
            for (int s0x = 0; s0x < nX; s0x += 16) {
                float2 q[16];
                #pragma unroll
                for (int k = 0; k < 16; ++k) {
                    int s = s0x + k;
                    q[k] = SVX[s < nX ? s : nX - 1];    // dup-pad idempotent
                }
                float a[16];
                #pragma unroll
                for (int k = 0; k < 16; ++k)
                    a[k] = lAj[(size_t)__float_as_int(q[k].y) * NT];
                #pragma unroll
                for (int k = 0; k < 16; ++k) {
                    float sc = q[k].x + a[k];
                    int   is = __float_as_int(q[k].y);
                    if (sc > mval || (sc == mval && is < bidx)) { mval = sc; bidx = is; }
                }
            }
        }
        float vn = mval + e;                 // single-rounded == ref
        __builtin_nontemporal_store((unsigned short)bidx, bp + (size_t)t * NT + j);
        if (t == TT - 1) vlast[j] = vn;
        v = vn;
    }

    // ---- diagnostics: P = min(255,cyc>>8)*16 + min(15, mean_n>>4) ----
    // decode: P = 2*(WRITE_KB - 8193); cb = P>>4 (256-cy buckets); nb = P&15.
    if (tid == 0) {
        long long cyc = (clock64() - c0) / (long long)(TT - 1);
        int cb = (int)(cyc >> 8); if (cb > 255) cb = 255; if (cb < 0) cb = 0;
        int mn = (int)(nAcc / (long long)(TT - 1)); if (mn > 511) mn = 511;
        int nb = mn >> 4; if (nb > 15) nb = 15;
        Pshare = cb * 16 + nb;
    }
    __syncthreads();
    const int P = Pshare;                    // <= 4095 pages (fits emis region)
    for (int pg = 0; pg < P; ++pg) {
        unsigned long long val = ((unsigned long long)pg << 32) | (unsigned)tid;
        __builtin_nontemporal_store(val,
            (unsigned long long*)((char*)scratch + (size_t)pg * 4096) + tid);
    }
}

// ---- backtrace: per-segment map composition (verified exact) ----
__launch_bounds__(NT, 1)
__global__ void bt_maps(const unsigned short* __restrict__ bp,
                        unsigned short* __restrict__ maps) {
    __shared__ unsigned short bps[BT_L * NT];
    const int s = blockIdx.x;
    const int tlo = BT_L * s + 1;
    int thi = BT_L * (s + 1); if (thi > TT - 1) thi = TT - 1;
    const int nt = thi - tlo + 1;
    for (int k = threadIdx.x; k < nt * NT; k += NT)
        bps[k] = bp[(size_t)tlo * NT + k];
    __syncthreads();
    int cur = threadIdx.x;
    for (int r = nt - 1; r >= 0; --r) cur = bps[r * NT + cur];
    maps[s * NT + threadIdx.x] = (unsigned short)cur;
}

__launch_bounds__(NT, 1)
__global__ void bt_bound(const float* __restrict__ vlast,
                         const unsigned short* __restrict__ maps,
                         int* __restrict__ bound) {
    __shared__ float sv[NT];
    __shared__ int   si[NT];
    int j = threadIdx.x;
    sv[j] = vlast[j]; si[j] = j;
    __syncthreads();
    for (int off = NT / 2; off > 0; off >>= 1) {
        if (j < off) {
            float v2 = sv[j + off]; int i2 = si[j + off];
            if (v2 > sv[j] || (v2 == sv[j] && i2 < si[j])) { sv[j] = v2; si[j] = i2; }
        }
        __syncthreads();
    }
    if (j == 0) {
        int cur = si[0];
        bound[BT_S] = cur;
        for (int s = BT_S - 1; s >= 0; --s) {
            cur = maps[s * NT + cur];
            bound[s] = cur;
        }
    }
}

__launch_bounds__(NT, 1)
__global__ void bt_path(const unsigned short* __restrict__ bp,
                        const int* __restrict__ bound,
                        int* __restrict__ path) {
    __shared__ unsigned short bps[BT_L * NT];
    const int s = blockIdx.x;
    const int tlo = BT_L * s + 1;
    int thi = BT_L * (s + 1); if (thi > TT - 1) thi = TT - 1;
    const int nt = thi - tlo + 1;
    for (int k = threadIdx.x; k < nt * NT; k += NT)
        bps[k] = bp[(size_t)tlo * NT + k];
    __syncthreads();
    if (threadIdx.x == 0) {
        int cur = bound[s + 1];
        if (s == BT_S - 1) path[TT - 1] = cur;
        for (int r = nt - 1; r >= 0; --r) {
            cur = bps[r * NT + cur];
            path[tlo - 1 + r] = cur;
        }
    }
}

extern "C" void kernel_launch(void* const* d_in, const int* in_sizes, int n_in,
                              void* d_out, int out_size, void* d_ws, size_t ws_size,
                              hipStream_t stream) {
    const int*   tok = (const int*)d_in[0];
    const float* A   = (const float*)d_in[1];
    const float* B   = (const float*)d_in[2];
    const float* Pi  = (const float*)d_in[3];
    int* path = (int*)d_out;
    char* ws = (char*)d_ws;
    if (ws_size < (size_t)WS_NEED) return;

    float* logPi          = (float*)(ws + WS_LOGPI);
    float* vlast          = (float*)(ws + WS_VLAST);
    int*   bound          = (int*)(ws + WS_BOUND);
    float* rowmax         = (float*)(ws + WS_ROWMAX);
    unsigned short* maps  = (unsigned short*)(ws + WS_MAPS);
    float* lA             = (float*)(ws + WS_LA);
    float* emis           = (float*)(ws + WS_EMIS);
    unsigned short* bpp   = (unsigned short*)(ws + WS_BP);

    prep_logs  <<<(NT * NT + NT + 255) / 256, 256, 0, stream>>>(A, Pi, lA, logPi);
    prep_emis  <<<(TT * NT) / 256,            256, 0, stream>>>(B, tok, emis);
    prep_rowmax<<<NT, 256, 0, stream>>>(lA, rowmax);
    viterbi_fwd_exact<<<1, NT, 0, stream>>>(lA, rowmax, emis, logPi, bpp, vlast,
                                            emis /*diag scratch*/);
    bt_maps  <<<BT_S, NT, 0, stream>>>(bpp, maps);
    bt_bound <<<1,    NT, 0, stream>>>(vlast, maps, bound);
    bt_path  <<<BT_S, NT, 0, stream>>>(bpp, bound, path);
}